// Round 6
// baseline (445.787 us; speedup 1.0000x reference)
//
#include <hip/hip_runtime.h>
#include <hip/hip_bf16.h>

#define NU 50000
#define NI 150000
#define NN 200000
#define NE 1250000
#define DD 64
#define NLAYERS 3
#define SCAN_B 1024
#define NB ((NN + SCAN_B - 1) / SCAN_B)   // 196
#define BT_STRIDE 232                      // bf16; 464B row: 16B-aligned, <=2-way banks on frag reads

typedef __attribute__((ext_vector_type(8))) short bf16x8;
typedef __attribute__((ext_vector_type(4))) float f32x4;

static __device__ __forceinline__ unsigned short f2b(float x) {
  __hip_bfloat16 h = __float2bfloat16(x);  // RNE
  return *reinterpret_cast<unsigned short*>(&h);
}

static __device__ __forceinline__ unsigned int pack2(float lo, float hi) {
  return (unsigned int)f2b(lo) | ((unsigned int)f2b(hi) << 16);
}

static __device__ __forceinline__ float blo(unsigned int u) { return __uint_as_float(u << 16); }
static __device__ __forceinline__ float bhi(unsigned int u) { return __uint_as_float(u & 0xffff0000u); }

// elementwise bf16x8 * bf16x8 -> bf16x8 (via f32)
static __device__ __forceinline__ bf16x8 mulbf8(bf16x8 a, bf16x8 b) {
  union { bf16x8 v; unsigned int u[4]; } A, B, R;
  A.v = a; B.v = b;
#pragma unroll
  for (int i = 0; i < 4; ++i) {
    R.u[i] = pack2(blo(A.u[i]) * blo(B.u[i]), bhi(A.u[i]) * bhi(B.u[i]));
  }
  return R.v;
}

// ---- zero cnt (in-graph hipMemsetAsync was pathologically slow) ----
__global__ __launch_bounds__(256) void k_zero(int* __restrict__ p) {
  int i = blockIdx.x * 256 + threadIdx.x;
  if (i < NN) p[i] = 0;
}

// ---- W^T bf16 prep: WtBf[l][n][j] = bf16(Wcat_l[j][n]), j in [0,192) ----
__global__ __launch_bounds__(256) void k_wprep(const float* __restrict__ Ws,
                                               unsigned short* __restrict__ WtBf) {
  int t = blockIdx.x * 256 + threadIdx.x;
  if (t >= 3 * 64 * 192) return;
  int j = t % 192;
  int n = (t / 192) & 63;
  int lyr = t / (192 * 64);
  WtBf[t] = f2b(Ws[((size_t)lyr * 3 + (j >> 6)) * 4096 + (size_t)(j & 63) * 64 + n]);
}

// ---- init: out[:, 0:64] = concat(user_emb, item_emb); also bf16 copy ----
__global__ __launch_bounds__(256) void k_init(const float4* __restrict__ ue,
                                              const float4* __restrict__ ie,
                                              float4* __restrict__ out4,
                                              uint2* __restrict__ ebf2) {
  int gid = blockIdx.x * 256 + threadIdx.x;
  if (gid >= NN * 16) return;
  int row = gid >> 4, q = gid & 15;
  float4 v = (row < NU) ? ue[(size_t)row * 16 + q] : ie[(size_t)(row - NU) * 16 + q];
  out4[(size_t)row * 64 + q] = v;  // out row stride = 256 floats = 64 float4
  uint2 b; b.x = pack2(v.x, v.y); b.y = pack2(v.z, v.w);
  ebf2[(size_t)row * 16 + q] = b;  // ebf row = 64 bf16 = 16 uint2
}

// ---- CSR build ----
__global__ __launch_bounds__(256) void k_hist(const int* __restrict__ dst, int* __restrict__ cnt) {
  int e = blockIdx.x * 256 + threadIdx.x;
  if (e < NE) atomicAdd(&cnt[dst[e]], 1);
}

__global__ __launch_bounds__(SCAN_B) void k_scan1(const int* __restrict__ cnt,
                                                  int* __restrict__ local,
                                                  int* __restrict__ btot) {
  __shared__ int sm[SCAN_B];
  int t = threadIdx.x;
  int i = blockIdx.x * SCAN_B + t;
  int v = (i < NN) ? cnt[i] : 0;
  sm[t] = v;
  __syncthreads();
  for (int off = 1; off < SCAN_B; off <<= 1) {
    int x = (t >= off) ? sm[t - off] : 0;
    __syncthreads();
    sm[t] += x;
    __syncthreads();
  }
  if (i < NN) local[i] = sm[t] - v;              // exclusive within block
  if (t == SCAN_B - 1) btot[blockIdx.x] = sm[t]; // block total
}

__global__ __launch_bounds__(256) void k_scan2(int* __restrict__ btot) {
  __shared__ int sm[256];
  int t = threadIdx.x;
  int v = (t < NB) ? btot[t] : 0;
  sm[t] = v;
  __syncthreads();
  for (int off = 1; off < 256; off <<= 1) {
    int x = (t >= off) ? sm[t - off] : 0;
    __syncthreads();
    sm[t] += x;
    __syncthreads();
  }
  if (t < NB) btot[t] = sm[t] - v;  // exclusive block offsets
}

__global__ __launch_bounds__(256) void k_finalize(const int* __restrict__ local,
                                                  const int* __restrict__ btot,
                                                  int* __restrict__ row_start,
                                                  int* __restrict__ cursor) {
  int i = blockIdx.x * 256 + threadIdx.x;
  if (i < NN) {
    int v = local[i] + btot[i / SCAN_B];
    row_start[i] = v;
    cursor[i] = v;
  }
  if (i == 0) row_start[NN] = NE;
}

__global__ __launch_bounds__(256) void k_fill(const int* __restrict__ src,
                                              const int* __restrict__ dst,
                                              const float* __restrict__ w,
                                              int* __restrict__ cursor,
                                              int2* __restrict__ csr_pack) {
  int e = blockIdx.x * 256 + threadIdx.x;
  if (e < NE) {
    int p = atomicAdd(&cursor[dst[e]], 1);
    int2 pk; pk.x = src[e]; pk.y = __float_as_int(w[e]);
    csr_pack[p] = pk;
  }
}

// ---- SpMM: one wave per row; 16 edges issued in one shot (covers 99.7% rows) ----
// lane = 32*h + c: h = edge parity, c = col-pair (cols 2c, 2c+1)
__global__ __launch_bounds__(256) void k_spmm(const int* __restrict__ row_start,
                                              const int2* __restrict__ csr_pack,
                                              const unsigned int* __restrict__ ebf, // [NN][32] uint (64 bf16)
                                              unsigned int* __restrict__ t1bf) {   // [NN][32] uint (64 bf16)
  int gid = blockIdx.x * 256 + threadIdx.x;
  int row = gid >> 6;
  if (row >= NN) return;
  int l = gid & 63;
  int h = l >> 5;
  int c = l & 31;
  int s0 = row_start[row];
  int s1 = row_start[row + 1];
  float a0 = 0.f, a1 = 0.f;

  // one 16-deep round: edges s0 + 2*i + h, i=0..7; clamped slots hit edge 0 (hot line, ~free)
  int2 p0, p1, p2, p3, p4, p5, p6, p7;
  {
    int j;
    j = s0 + 0  + h; p0 = csr_pack[j < s1 ? j : 0];
    j = s0 + 2  + h; p1 = csr_pack[j < s1 ? j : 0];
    j = s0 + 4  + h; p2 = csr_pack[j < s1 ? j : 0];
    j = s0 + 6  + h; p3 = csr_pack[j < s1 ? j : 0];
    j = s0 + 8  + h; p4 = csr_pack[j < s1 ? j : 0];
    j = s0 + 10 + h; p5 = csr_pack[j < s1 ? j : 0];
    j = s0 + 12 + h; p6 = csr_pack[j < s1 ? j : 0];
    j = s0 + 14 + h; p7 = csr_pack[j < s1 ? j : 0];
  }
  unsigned int v0 = ebf[(size_t)p0.x * 32 + c];
  unsigned int v1 = ebf[(size_t)p1.x * 32 + c];
  unsigned int v2 = ebf[(size_t)p2.x * 32 + c];
  unsigned int v3 = ebf[(size_t)p3.x * 32 + c];
  unsigned int v4 = ebf[(size_t)p4.x * 32 + c];
  unsigned int v5 = ebf[(size_t)p5.x * 32 + c];
  unsigned int v6 = ebf[(size_t)p6.x * 32 + c];
  unsigned int v7 = ebf[(size_t)p7.x * 32 + c];
  {
    float wt;
    wt = (s0 + 0  + h < s1) ? __int_as_float(p0.y) : 0.f; a0 = fmaf(wt, blo(v0), a0); a1 = fmaf(wt, bhi(v0), a1);
    wt = (s0 + 2  + h < s1) ? __int_as_float(p1.y) : 0.f; a0 = fmaf(wt, blo(v1), a0); a1 = fmaf(wt, bhi(v1), a1);
    wt = (s0 + 4  + h < s1) ? __int_as_float(p2.y) : 0.f; a0 = fmaf(wt, blo(v2), a0); a1 = fmaf(wt, bhi(v2), a1);
    wt = (s0 + 6  + h < s1) ? __int_as_float(p3.y) : 0.f; a0 = fmaf(wt, blo(v3), a0); a1 = fmaf(wt, bhi(v3), a1);
    wt = (s0 + 8  + h < s1) ? __int_as_float(p4.y) : 0.f; a0 = fmaf(wt, blo(v4), a0); a1 = fmaf(wt, bhi(v4), a1);
    wt = (s0 + 10 + h < s1) ? __int_as_float(p5.y) : 0.f; a0 = fmaf(wt, blo(v5), a0); a1 = fmaf(wt, bhi(v5), a1);
    wt = (s0 + 12 + h < s1) ? __int_as_float(p6.y) : 0.f; a0 = fmaf(wt, blo(v6), a0); a1 = fmaf(wt, bhi(v6), a1);
    wt = (s0 + 14 + h < s1) ? __int_as_float(p7.y) : 0.f; a0 = fmaf(wt, blo(v7), a0); a1 = fmaf(wt, bhi(v7), a1);
  }
  // rare tail (deg > 16): 0.3% of rows
  for (int base = s0 + 16; base < s1; base += 8) {
    int j0 = base + 0 + h, j1 = base + 2 + h, j2 = base + 4 + h, j3 = base + 6 + h;
    int2 q0 = csr_pack[j0 < s1 ? j0 : 0];
    int2 q1 = csr_pack[j1 < s1 ? j1 : 0];
    int2 q2 = csr_pack[j2 < s1 ? j2 : 0];
    int2 q3 = csr_pack[j3 < s1 ? j3 : 0];
    unsigned int u0 = ebf[(size_t)q0.x * 32 + c];
    unsigned int u1 = ebf[(size_t)q1.x * 32 + c];
    unsigned int u2 = ebf[(size_t)q2.x * 32 + c];
    unsigned int u3 = ebf[(size_t)q3.x * 32 + c];
    float x0 = (j0 < s1) ? __int_as_float(q0.y) : 0.f;
    float x1 = (j1 < s1) ? __int_as_float(q1.y) : 0.f;
    float x2 = (j2 < s1) ? __int_as_float(q2.y) : 0.f;
    float x3 = (j3 < s1) ? __int_as_float(q3.y) : 0.f;
    a0 = fmaf(x0, blo(u0), a0); a1 = fmaf(x0, bhi(u0), a1);
    a0 = fmaf(x1, blo(u1), a0); a1 = fmaf(x1, bhi(u1), a1);
    a0 = fmaf(x2, blo(u2), a0); a1 = fmaf(x2, bhi(u2), a1);
    a0 = fmaf(x3, blo(u3), a0); a1 = fmaf(x3, bhi(u3), a1);
  }

  a0 += __shfl_xor(a0, 32, 64);
  a1 += __shfl_xor(a1, 32, 64);
  if (h == 0) t1bf[(size_t)row * 32 + c] = pack2(a0, a1);
}

// ---- GEMM via MFMA: inter = [t1 | t1*e | e] @ [W1;W2;W3] + b; leaky; l2norm ----
// wave = 16 rows; block = 4 waves = 64 rows; grid = 3125
__global__ __launch_bounds__(256) void k_row_mfma(const unsigned int* __restrict__ t1bf,
                                                  const unsigned int* __restrict__ ebf,
                                                  const unsigned short* __restrict__ WtBf,
                                                  const float* __restrict__ bs,
                                                  float* __restrict__ out,
                                                  unsigned short* __restrict__ ebf_next,
                                                  int layer, int wbf) {
  __shared__ unsigned short Bt[64][BT_STRIDE];  // Bt[n][j] = bf16(Wcat[j][n]), j in [0,192)
  const int tid = threadIdx.x;
  {
    // stage 64x192 bf16 tile (24KB) from prepacked global: fully coalesced uint4 copies
    const uint4* __restrict__ src = reinterpret_cast<const uint4*>(WtBf + (size_t)layer * 64 * 192);
#pragma unroll
    for (int ch = tid; ch < 1536; ch += 256) {
      int rown = ch / 24, k = ch % 24;
      *reinterpret_cast<uint4*>(&Bt[rown][k * 8]) = src[ch];
    }
  }
  __syncthreads();

  const int l = tid & 63;
  const int wv = tid >> 6;
  const int g = l >> 4;    // A: k-group; D: row-group
  const int li = l & 15;   // A: row; D: col
  const int rowbase = blockIdx.x * 64 + wv * 16;
  const int r = rowbase + li;

  // A fragments straight from bf16 buffers: lane holds 8 contiguous k at 8*g / 32+8*g
  const unsigned short* __restrict__ t1b = reinterpret_cast<const unsigned short*>(t1bf);
  const unsigned short* __restrict__ eb = reinterpret_cast<const unsigned short*>(ebf);
  bf16x8 A0 = *reinterpret_cast<const bf16x8*>(t1b + (size_t)r * 64 + 8 * g);
  bf16x8 A1 = *reinterpret_cast<const bf16x8*>(t1b + (size_t)r * 64 + 32 + 8 * g);
  bf16x8 E0 = *reinterpret_cast<const bf16x8*>(eb + (size_t)r * 64 + 8 * g);
  bf16x8 E1 = *reinterpret_cast<const bf16x8*>(eb + (size_t)r * 64 + 32 + 8 * g);
  bf16x8 T0 = mulbf8(A0, E0);
  bf16x8 T1 = mulbf8(A1, E1);

  const float* __restrict__ bsl = bs + (size_t)layer * 3 * 64;
  f32x4 acc[4];
#pragma unroll
  for (int f = 0; f < 4; ++f) {
    int n = f * 16 + li;
    float bv = bsl[n] + bsl[64 + n] + bsl[128 + n];
    acc[f] = (f32x4){bv, bv, bv, bv};
  }

  bf16x8 Afr[6] = {A0, A1, T0, T1, E0, E1};
#pragma unroll
  for (int s = 0; s < 6; ++s) {
#pragma unroll
    for (int f = 0; f < 4; ++f) {
      const bf16x8 Bf = *reinterpret_cast<const bf16x8*>(&Bt[f * 16 + li][s * 32 + 8 * g]);
      acc[f] = __builtin_amdgcn_mfma_f32_16x16x32_bf16(Afr[s], Bf, acc[f], 0, 0, 0);
    }
  }

  // epilogue: leaky relu, row L2 norm (row = rowbase + 4*g + reg, col = f*16 + li)
  float p[4];
#pragma unroll
  for (int reg = 0; reg < 4; ++reg) {
    float ssum = 0.f;
#pragma unroll
    for (int f = 0; f < 4; ++f) {
      float x = acc[f][reg];
      x = (x >= 0.f) ? x : 0.01f * x;
      acc[f][reg] = x;
      ssum = fmaf(x, x, ssum);
    }
    p[reg] = ssum;
  }
#pragma unroll
  for (int off = 1; off < 16; off <<= 1) {
#pragma unroll
    for (int reg = 0; reg < 4; ++reg) p[reg] += __shfl_xor(p[reg], off, 64);
  }
  float inv[4];
#pragma unroll
  for (int reg = 0; reg < 4; ++reg) inv[reg] = 1.0f / fmaxf(sqrtf(p[reg]), 1e-12f);

  float* __restrict__ ob = out + (size_t)(layer + 1) * 64;
#pragma unroll
  for (int reg = 0; reg < 4; ++reg) {
#pragma unroll
    for (int f = 0; f < 4; ++f) {
      float val = acc[f][reg] * inv[reg];
      ob[(size_t)(rowbase + 4 * g + reg) * 256 + f * 16 + li] = val;
      if (wbf) ebf_next[(size_t)(rowbase + 4 * g + reg) * 64 + f * 16 + li] = f2b(val);
    }
  }
}

extern "C" void kernel_launch(void* const* d_in, const int* in_sizes, int n_in,
                              void* d_out, int out_size, void* d_ws, size_t ws_size,
                              hipStream_t stream) {
  const int* edge_src = (const int*)d_in[0];
  const int* edge_dst = (const int*)d_in[1];
  const float* edge_w = (const float*)d_in[2];
  const float* user_emb = (const float*)d_in[3];
  const float* item_emb = (const float*)d_in[4];
  const float* Ws = (const float*)d_in[5];
  const float* bs = (const float*)d_in[6];
  float* out = (float*)d_out;

  char* w = (char*)d_ws;
  unsigned int* ebfA = (unsigned int*)w; w += (size_t)NN * 32 * 4;  // 25.6 MB
  unsigned int* ebfB = (unsigned int*)w; w += (size_t)NN * 32 * 4;  // 25.6 MB
  unsigned int* t1bf = (unsigned int*)w; w += (size_t)NN * 32 * 4;  // 25.6 MB
  int2* csr_pack = (int2*)w;      w += (size_t)NE * 8;              // 10 MB
  unsigned short* WtBf = (unsigned short*)w; w += (size_t)3 * 64 * 192 * 2;
  int* cnt = (int*)w;             w += (size_t)NN * 4;
  int* local = (int*)w;           w += (size_t)NN * 4;
  int* row_start = (int*)w;       w += (size_t)(NN + 4) * 4;
  int* cursor = (int*)w;          w += (size_t)NN * 4;
  int* btot = (int*)w;            w += 256 * 4;

  k_zero<<<(NN + 255) / 256, 256, 0, stream>>>(cnt);
  k_wprep<<<(3 * 64 * 192 + 255) / 256, 256, 0, stream>>>(Ws, WtBf);
  k_init<<<(NN * 16 + 255) / 256, 256, 0, stream>>>(
      (const float4*)user_emb, (const float4*)item_emb, (float4*)out, (uint2*)ebfA);
  k_hist<<<(NE + 255) / 256, 256, 0, stream>>>(edge_dst, cnt);
  k_scan1<<<NB, SCAN_B, 0, stream>>>(cnt, local, btot);
  k_scan2<<<1, 256, 0, stream>>>(btot);
  k_finalize<<<(NN + 255) / 256, 256, 0, stream>>>(local, btot, row_start, cursor);
  k_fill<<<(NE + 255) / 256, 256, 0, stream>>>(edge_src, edge_dst, edge_w, cursor, csr_pack);

  // layer l reads ebfX, writes ebfY (double-buffered to avoid cross-block races)
  k_spmm<<<(NN * 64 + 255) / 256, 256, 0, stream>>>(row_start, csr_pack, ebfA, t1bf);
  k_row_mfma<<<NN / 64, 256, 0, stream>>>(t1bf, ebfA, WtBf, bs, out, (unsigned short*)ebfB, 0, 1);
  k_spmm<<<(NN * 64 + 255) / 256, 256, 0, stream>>>(row_start, csr_pack, ebfB, t1bf);
  k_row_mfma<<<NN / 64, 256, 0, stream>>>(t1bf, ebfB, WtBf, bs, out, (unsigned short*)ebfA, 1, 1);
  k_spmm<<<(NN * 64 + 255) / 256, 256, 0, stream>>>(row_start, csr_pack, ebfA, t1bf);
  k_row_mfma<<<NN / 64, 256, 0, stream>>>(t1bf, ebfA, WtBf, bs, out, (unsigned short*)ebfB, 2, 0);
}

// Round 7
// 410.963 us; speedup vs baseline: 1.0847x; 1.0847x over previous
//
#include <hip/hip_runtime.h>
#include <hip/hip_bf16.h>

#define NU 50000
#define NI 150000
#define NN 200000
#define NE 1250000
#define DD 64
#define NLAYERS 3
#define SCAN_B 1024
#define NB ((NN + SCAN_B - 1) / SCAN_B)   // 196
#define BT_STRIDE 232                      // bf16; 464B row: 16B-aligned, <=2-way banks on frag reads

typedef __attribute__((ext_vector_type(8))) short bf16x8;
typedef __attribute__((ext_vector_type(4))) float f32x4;

static __device__ __forceinline__ unsigned short f2b(float x) {
  __hip_bfloat16 h = __float2bfloat16(x);  // RNE
  return *reinterpret_cast<unsigned short*>(&h);
}

static __device__ __forceinline__ unsigned int pack2(float lo, float hi) {
  return (unsigned int)f2b(lo) | ((unsigned int)f2b(hi) << 16);
}

static __device__ __forceinline__ float blo(unsigned int u) { return __uint_as_float(u << 16); }
static __device__ __forceinline__ float bhi(unsigned int u) { return __uint_as_float(u & 0xffff0000u); }

// elementwise bf16x8 * bf16x8 -> bf16x8 (via f32)
static __device__ __forceinline__ bf16x8 mulbf8(bf16x8 a, bf16x8 b) {
  union { bf16x8 v; unsigned int u[4]; } A, B, R;
  A.v = a; B.v = b;
#pragma unroll
  for (int i = 0; i < 4; ++i) {
    R.u[i] = pack2(blo(A.u[i]) * blo(B.u[i]), bhi(A.u[i]) * bhi(B.u[i]));
  }
  return R.v;
}

// ---- zero cnt (in-graph hipMemsetAsync is pathologically slow) ----
__global__ __launch_bounds__(256) void k_zero(int* __restrict__ p) {
  int i = blockIdx.x * 256 + threadIdx.x;
  if (i < NN) p[i] = 0;
}

// ---- W^T bf16 prep: WtBf[l][n][j] = bf16(Wcat_l[j][n]), j in [0,192) ----
__global__ __launch_bounds__(256) void k_wprep(const float* __restrict__ Ws,
                                               unsigned short* __restrict__ WtBf) {
  int t = blockIdx.x * 256 + threadIdx.x;
  if (t >= 3 * 64 * 192) return;
  int j = t % 192;
  int n = (t / 192) & 63;
  int lyr = t / (192 * 64);
  WtBf[t] = f2b(Ws[((size_t)lyr * 3 + (j >> 6)) * 4096 + (size_t)(j & 63) * 64 + n]);
}

// ---- init: out[:, 0:64] = concat(user_emb, item_emb); also bf16 copy ----
__global__ __launch_bounds__(256) void k_init(const float4* __restrict__ ue,
                                              const float4* __restrict__ ie,
                                              float4* __restrict__ out4,
                                              uint2* __restrict__ ebf2) {
  int gid = blockIdx.x * 256 + threadIdx.x;
  if (gid >= NN * 16) return;
  int row = gid >> 4, q = gid & 15;
  float4 v = (row < NU) ? ue[(size_t)row * 16 + q] : ie[(size_t)(row - NU) * 16 + q];
  out4[(size_t)row * 64 + q] = v;  // out row stride = 256 floats = 64 float4
  uint2 b; b.x = pack2(v.x, v.y); b.y = pack2(v.z, v.w);
  ebf2[(size_t)row * 16 + q] = b;  // ebf row = 64 bf16 = 16 uint2
}

// ---- CSR build ----
__global__ __launch_bounds__(256) void k_hist(const int* __restrict__ dst, int* __restrict__ cnt) {
  int e = blockIdx.x * 256 + threadIdx.x;
  if (e < NE) atomicAdd(&cnt[dst[e]], 1);
}

__global__ __launch_bounds__(SCAN_B) void k_scan1(const int* __restrict__ cnt,
                                                  int* __restrict__ local,
                                                  int* __restrict__ btot) {
  __shared__ int sm[SCAN_B];
  int t = threadIdx.x;
  int i = blockIdx.x * SCAN_B + t;
  int v = (i < NN) ? cnt[i] : 0;
  sm[t] = v;
  __syncthreads();
  for (int off = 1; off < SCAN_B; off <<= 1) {
    int x = (t >= off) ? sm[t - off] : 0;
    __syncthreads();
    sm[t] += x;
    __syncthreads();
  }
  if (i < NN) local[i] = sm[t] - v;              // exclusive within block
  if (t == SCAN_B - 1) btot[blockIdx.x] = sm[t]; // block total
}

__global__ __launch_bounds__(256) void k_scan2(int* __restrict__ btot) {
  __shared__ int sm[256];
  int t = threadIdx.x;
  int v = (t < NB) ? btot[t] : 0;
  sm[t] = v;
  __syncthreads();
  for (int off = 1; off < 256; off <<= 1) {
    int x = (t >= off) ? sm[t - off] : 0;
    __syncthreads();
    sm[t] += x;
    __syncthreads();
  }
  if (t < NB) btot[t] = sm[t] - v;  // exclusive block offsets
}

__global__ __launch_bounds__(256) void k_finalize(const int* __restrict__ local,
                                                  const int* __restrict__ btot,
                                                  int* __restrict__ row_start,
                                                  int* __restrict__ cursor) {
  int i = blockIdx.x * 256 + threadIdx.x;
  if (i < NN) {
    int v = local[i] + btot[i / SCAN_B];
    row_start[i] = v;
    cursor[i] = v;
  }
  if (i == 0) row_start[NN] = NE;
}

__global__ __launch_bounds__(256) void k_fill(const int* __restrict__ src,
                                              const int* __restrict__ dst,
                                              const float* __restrict__ w,
                                              int* __restrict__ cursor,
                                              int2* __restrict__ csr_pack) {
  int e = blockIdx.x * 256 + threadIdx.x;
  if (e < NE) {
    int p = atomicAdd(&cursor[dst[e]], 1);
    int2 pk; pk.x = src[e]; pk.y = __float_as_int(w[e]);
    csr_pack[p] = pk;
  }
}

// ---- SpMM v3: one wave per row; 8 lanes x uint4 per edge row => 8 edges per VMEM instr ----
// lane l: eidx = l>>3 (edge within round), cb = l&7 (col-block: bf16 cols 8cb..8cb+7)
__global__ __launch_bounds__(256) void k_spmm(const int* __restrict__ row_start,
                                              const int2* __restrict__ csr_pack,
                                              const unsigned int* __restrict__ ebf, // [NN][32] uint (64 bf16)
                                              unsigned int* __restrict__ t1bf) {   // [NN][32] uint (64 bf16)
  int gid = blockIdx.x * 256 + threadIdx.x;
  int row = gid >> 6;
  if (row >= NN) return;
  const int l = gid & 63;
  const int eidx = l >> 3;
  const int cb = l & 7;
  int s0 = row_start[row];
  int s1 = row_start[row + 1];

  float a0 = 0.f, a1 = 0.f, a2 = 0.f, a3 = 0.f, a4 = 0.f, a5 = 0.f, a6 = 0.f, a7 = 0.f;

  if (s0 < s1) {
    // 2 rounds (16 edges) issued together: covers 99.7% of rows with zero serial latency chains
    int j0 = s0 + eidx, j1 = s0 + 8 + eidx;
    int2 p0 = csr_pack[j0 < s1 ? j0 : 0];
    int2 p1 = csr_pack[j1 < s1 ? j1 : 0];
    uint4 v0 = *reinterpret_cast<const uint4*>(ebf + (size_t)p0.x * 32 + cb * 4);
    uint4 v1 = *reinterpret_cast<const uint4*>(ebf + (size_t)p1.x * 32 + cb * 4);
    float w0 = (j0 < s1) ? __int_as_float(p0.y) : 0.f;
    float w1 = (j1 < s1) ? __int_as_float(p1.y) : 0.f;
    a0 = fmaf(w0, blo(v0.x), a0); a1 = fmaf(w0, bhi(v0.x), a1);
    a2 = fmaf(w0, blo(v0.y), a2); a3 = fmaf(w0, bhi(v0.y), a3);
    a4 = fmaf(w0, blo(v0.z), a4); a5 = fmaf(w0, bhi(v0.z), a5);
    a6 = fmaf(w0, blo(v0.w), a6); a7 = fmaf(w0, bhi(v0.w), a7);
    a0 = fmaf(w1, blo(v1.x), a0); a1 = fmaf(w1, bhi(v1.x), a1);
    a2 = fmaf(w1, blo(v1.y), a2); a3 = fmaf(w1, bhi(v1.y), a3);
    a4 = fmaf(w1, blo(v1.z), a4); a5 = fmaf(w1, bhi(v1.z), a5);
    a6 = fmaf(w1, blo(v1.w), a6); a7 = fmaf(w1, bhi(v1.w), a7);
    // rare tail (deg > 16): 0.3% of rows
    for (int base = s0 + 16; base < s1; base += 8) {
      int j = base + eidx;
      int2 p = csr_pack[j < s1 ? j : 0];
      uint4 v = *reinterpret_cast<const uint4*>(ebf + (size_t)p.x * 32 + cb * 4);
      float wt = (j < s1) ? __int_as_float(p.y) : 0.f;
      a0 = fmaf(wt, blo(v.x), a0); a1 = fmaf(wt, bhi(v.x), a1);
      a2 = fmaf(wt, blo(v.y), a2); a3 = fmaf(wt, bhi(v.y), a3);
      a4 = fmaf(wt, blo(v.z), a4); a5 = fmaf(wt, bhi(v.z), a5);
      a6 = fmaf(wt, blo(v.w), a6); a7 = fmaf(wt, bhi(v.w), a7);
    }
  }

  // reduce across the 8 edge-slots (lanes with same cb, stride 8 apart)
  a0 += __shfl_xor(a0, 8, 64);  a0 += __shfl_xor(a0, 16, 64);  a0 += __shfl_xor(a0, 32, 64);
  a1 += __shfl_xor(a1, 8, 64);  a1 += __shfl_xor(a1, 16, 64);  a1 += __shfl_xor(a1, 32, 64);
  a2 += __shfl_xor(a2, 8, 64);  a2 += __shfl_xor(a2, 16, 64);  a2 += __shfl_xor(a2, 32, 64);
  a3 += __shfl_xor(a3, 8, 64);  a3 += __shfl_xor(a3, 16, 64);  a3 += __shfl_xor(a3, 32, 64);
  a4 += __shfl_xor(a4, 8, 64);  a4 += __shfl_xor(a4, 16, 64);  a4 += __shfl_xor(a4, 32, 64);
  a5 += __shfl_xor(a5, 8, 64);  a5 += __shfl_xor(a5, 16, 64);  a5 += __shfl_xor(a5, 32, 64);
  a6 += __shfl_xor(a6, 8, 64);  a6 += __shfl_xor(a6, 16, 64);  a6 += __shfl_xor(a6, 32, 64);
  a7 += __shfl_xor(a7, 8, 64);  a7 += __shfl_xor(a7, 16, 64);  a7 += __shfl_xor(a7, 32, 64);

  if (l < 8) {  // lane cb==l stores cols 8l..8l+7: 8 lanes x 16B = coalesced 128B row
    uint4 st;
    st.x = pack2(a0, a1); st.y = pack2(a2, a3); st.z = pack2(a4, a5); st.w = pack2(a6, a7);
    *reinterpret_cast<uint4*>(t1bf + (size_t)row * 32 + l * 4) = st;
  }
}

// ---- GEMM via MFMA: inter = [t1 | t1*e | e] @ [W1;W2;W3] + b; leaky; l2norm ----
// wave = 16 rows; block = 4 waves = 64 rows; grid = 3125
__global__ __launch_bounds__(256) void k_row_mfma(const unsigned int* __restrict__ t1bf,
                                                  const unsigned int* __restrict__ ebf,
                                                  const unsigned short* __restrict__ WtBf,
                                                  const float* __restrict__ bs,
                                                  float* __restrict__ out,
                                                  unsigned short* __restrict__ ebf_next,
                                                  int layer, int wbf) {
  __shared__ unsigned short Bt[64][BT_STRIDE];  // Bt[n][j] = bf16(Wcat[j][n]), j in [0,192)
  const int tid = threadIdx.x;
  {
    // stage 64x192 bf16 tile (24KB) from prepacked global: fully coalesced uint4 copies
    const uint4* __restrict__ src = reinterpret_cast<const uint4*>(WtBf + (size_t)layer * 64 * 192);
#pragma unroll
    for (int ch = tid; ch < 1536; ch += 256) {
      int rown = ch / 24, k = ch % 24;
      *reinterpret_cast<uint4*>(&Bt[rown][k * 8]) = src[ch];
    }
  }
  __syncthreads();

  const int l = tid & 63;
  const int wv = tid >> 6;
  const int g = l >> 4;    // A: k-group; D: row-group
  const int li = l & 15;   // A: row; D: col
  const int rowbase = blockIdx.x * 64 + wv * 16;
  const int r = rowbase + li;

  // A fragments straight from bf16 buffers: lane holds 8 contiguous k at 8*g / 32+8*g
  const unsigned short* __restrict__ t1b = reinterpret_cast<const unsigned short*>(t1bf);
  const unsigned short* __restrict__ eb = reinterpret_cast<const unsigned short*>(ebf);
  bf16x8 A0 = *reinterpret_cast<const bf16x8*>(t1b + (size_t)r * 64 + 8 * g);
  bf16x8 A1 = *reinterpret_cast<const bf16x8*>(t1b + (size_t)r * 64 + 32 + 8 * g);
  bf16x8 E0 = *reinterpret_cast<const bf16x8*>(eb + (size_t)r * 64 + 8 * g);
  bf16x8 E1 = *reinterpret_cast<const bf16x8*>(eb + (size_t)r * 64 + 32 + 8 * g);
  bf16x8 T0 = mulbf8(A0, E0);
  bf16x8 T1 = mulbf8(A1, E1);

  const float* __restrict__ bsl = bs + (size_t)layer * 3 * 64;
  f32x4 acc[4];
#pragma unroll
  for (int f = 0; f < 4; ++f) {
    int n = f * 16 + li;
    float bv = bsl[n] + bsl[64 + n] + bsl[128 + n];
    acc[f] = (f32x4){bv, bv, bv, bv};
  }

  bf16x8 Afr[6] = {A0, A1, T0, T1, E0, E1};
#pragma unroll
  for (int s = 0; s < 6; ++s) {
#pragma unroll
    for (int f = 0; f < 4; ++f) {
      const bf16x8 Bf = *reinterpret_cast<const bf16x8*>(&Bt[f * 16 + li][s * 32 + 8 * g]);
      acc[f] = __builtin_amdgcn_mfma_f32_16x16x32_bf16(Afr[s], Bf, acc[f], 0, 0, 0);
    }
  }

  // epilogue: leaky relu, row L2 norm (row = rowbase + 4*g + reg, col = f*16 + li)
  float p[4];
#pragma unroll
  for (int reg = 0; reg < 4; ++reg) {
    float ssum = 0.f;
#pragma unroll
    for (int f = 0; f < 4; ++f) {
      float x = acc[f][reg];
      x = (x >= 0.f) ? x : 0.01f * x;
      acc[f][reg] = x;
      ssum = fmaf(x, x, ssum);
    }
    p[reg] = ssum;
  }
#pragma unroll
  for (int off = 1; off < 16; off <<= 1) {
#pragma unroll
    for (int reg = 0; reg < 4; ++reg) p[reg] += __shfl_xor(p[reg], off, 64);
  }
  float inv[4];
#pragma unroll
  for (int reg = 0; reg < 4; ++reg) inv[reg] = 1.0f / fmaxf(sqrtf(p[reg]), 1e-12f);

  float* __restrict__ ob = out + (size_t)(layer + 1) * 64;
#pragma unroll
  for (int reg = 0; reg < 4; ++reg) {
#pragma unroll
    for (int f = 0; f < 4; ++f) {
      float val = acc[f][reg] * inv[reg];
      ob[(size_t)(rowbase + 4 * g + reg) * 256 + f * 16 + li] = val;
      if (wbf) ebf_next[(size_t)(rowbase + 4 * g + reg) * 64 + f * 16 + li] = f2b(val);
    }
  }
}

extern "C" void kernel_launch(void* const* d_in, const int* in_sizes, int n_in,
                              void* d_out, int out_size, void* d_ws, size_t ws_size,
                              hipStream_t stream) {
  const int* edge_src = (const int*)d_in[0];
  const int* edge_dst = (const int*)d_in[1];
  const float* edge_w = (const float*)d_in[2];
  const float* user_emb = (const float*)d_in[3];
  const float* item_emb = (const float*)d_in[4];
  const float* Ws = (const float*)d_in[5];
  const float* bs = (const float*)d_in[6];
  float* out = (float*)d_out;

  char* w = (char*)d_ws;
  unsigned int* ebfA = (unsigned int*)w; w += (size_t)NN * 32 * 4;  // 25.6 MB
  unsigned int* ebfB = (unsigned int*)w; w += (size_t)NN * 32 * 4;  // 25.6 MB
  unsigned int* t1bf = (unsigned int*)w; w += (size_t)NN * 32 * 4;  // 25.6 MB
  int2* csr_pack = (int2*)w;      w += (size_t)NE * 8;              // 10 MB
  unsigned short* WtBf = (unsigned short*)w; w += (size_t)3 * 64 * 192 * 2;
  int* cnt = (int*)w;             w += (size_t)NN * 4;
  int* local = (int*)w;           w += (size_t)NN * 4;
  int* row_start = (int*)w;       w += (size_t)(NN + 4) * 4;
  int* cursor = (int*)w;          w += (size_t)NN * 4;
  int* btot = (int*)w;            w += 256 * 4;

  k_zero<<<(NN + 255) / 256, 256, 0, stream>>>(cnt);
  k_wprep<<<(3 * 64 * 192 + 255) / 256, 256, 0, stream>>>(Ws, WtBf);
  k_init<<<(NN * 16 + 255) / 256, 256, 0, stream>>>(
      (const float4*)user_emb, (const float4*)item_emb, (float4*)out, (uint2*)ebfA);
  k_hist<<<(NE + 255) / 256, 256, 0, stream>>>(edge_dst, cnt);
  k_scan1<<<NB, SCAN_B, 0, stream>>>(cnt, local, btot);
  k_scan2<<<1, 256, 0, stream>>>(btot);
  k_finalize<<<(NN + 255) / 256, 256, 0, stream>>>(local, btot, row_start, cursor);
  k_fill<<<(NE + 255) / 256, 256, 0, stream>>>(edge_src, edge_dst, edge_w, cursor, csr_pack);

  // layer l reads ebfX, writes ebfY (double-buffered to avoid cross-block races)
  k_spmm<<<(NN * 64 + 255) / 256, 256, 0, stream>>>(row_start, csr_pack, ebfA, t1bf);
  k_row_mfma<<<NN / 64, 256, 0, stream>>>(t1bf, ebfA, WtBf, bs, out, (unsigned short*)ebfB, 0, 1);
  k_spmm<<<(NN * 64 + 255) / 256, 256, 0, stream>>>(row_start, csr_pack, ebfB, t1bf);
  k_row_mfma<<<NN / 64, 256, 0, stream>>>(t1bf, ebfB, WtBf, bs, out, (unsigned short*)ebfA, 1, 1);
  k_spmm<<<(NN * 64 + 255) / 256, 256, 0, stream>>>(row_start, csr_pack, ebfA, t1bf);
  k_row_mfma<<<NN / 64, 256, 0, stream>>>(t1bf, ebfA, WtBf, bs, out, (unsigned short*)ebfB, 2, 0);
}